// Round 1
// baseline (599.490 us; speedup 1.0000x reference)
//
#include <hip/hip_runtime.h>
#include <hip/hip_bf16.h>
#include <math.h>

#define NEG_SLOPE 0.2f
#define EPS_NRM 1e-12f
#define K_IN 256
#define C_OUT 64

// ---------------------------------------------------------------------------
// Kernel A: h = x @ W, plus fused a_src = h.att_src, a_dst = h.att_dst.
// One thread per row: 64 fp32 accumulators in VGPRs; W rows are wave-uniform
// loads (compiler scalarizes to s_load -> constant cache), x row streamed as
// float4 per lane.
// ---------------------------------------------------------------------------
__global__ __launch_bounds__(256) void gemm_att(
    const float* __restrict__ x, const float* __restrict__ W,
    const float* __restrict__ att_s, const float* __restrict__ att_d,
    float* __restrict__ h, float* __restrict__ a_src_arr,
    float* __restrict__ a_dst_arr, int N)
{
    int r = blockIdx.x * blockDim.x + threadIdx.x;
    if (r >= N) return;

    float acc[C_OUT];
#pragma unroll
    for (int o = 0; o < C_OUT; ++o) acc[o] = 0.f;

    const float* xr = x + (size_t)r * K_IN;

    for (int k = 0; k < K_IN; k += 4) {
        float4 xv = *(const float4*)(xr + k);
#pragma unroll
        for (int kk = 0; kk < 4; ++kk) {
            float xs = (kk == 0) ? xv.x : (kk == 1) ? xv.y : (kk == 2) ? xv.z : xv.w;
            const float* wrow = W + (size_t)(k + kk) * C_OUT;
#pragma unroll
            for (int j = 0; j < 16; ++j) {
                float4 wv = *(const float4*)(wrow + 4 * j);
                acc[4 * j + 0] += xs * wv.x;
                acc[4 * j + 1] += xs * wv.y;
                acc[4 * j + 2] += xs * wv.z;
                acc[4 * j + 3] += xs * wv.w;
            }
        }
    }

    // fused attention scores
    float asum = 0.f, dsum = 0.f;
#pragma unroll
    for (int j = 0; j < 16; ++j) {
        float4 av = *(const float4*)(att_s + 4 * j);
        float4 dv = *(const float4*)(att_d + 4 * j);
        asum += acc[4 * j + 0] * av.x + acc[4 * j + 1] * av.y +
                acc[4 * j + 2] * av.z + acc[4 * j + 3] * av.w;
        dsum += acc[4 * j + 0] * dv.x + acc[4 * j + 1] * dv.y +
                acc[4 * j + 2] * dv.z + acc[4 * j + 3] * dv.w;
    }
    a_src_arr[r] = asum;
    a_dst_arr[r] = dsum;

    float* hr = h + (size_t)r * C_OUT;
#pragma unroll
    for (int j = 0; j < 16; ++j) {
        float4 hv = make_float4(acc[4 * j + 0], acc[4 * j + 1],
                                acc[4 * j + 2], acc[4 * j + 3]);
        *(float4*)(hr + 4 * j) = hv;
    }
}

// ---------------------------------------------------------------------------
// CSR build: histogram of dst, 3-kernel exclusive scan (incl. +1 self loop),
// scatter src ids into buckets.
// ---------------------------------------------------------------------------
__global__ __launch_bounds__(256) void count_dst(
    const int* __restrict__ dst, int* __restrict__ cnt, int E)
{
    int i = blockIdx.x * blockDim.x + threadIdx.x;
    if (i < E) atomicAdd(&cnt[dst[i]], 1);
}

// 1024 items per block, 4 per thread
__global__ __launch_bounds__(256) void scan_p1(
    const int* __restrict__ cnt, int* __restrict__ partials, int n)
{
    int b = blockIdx.x, t = threadIdx.x;
    int base = b * 1024;
    int s = 0;
#pragma unroll
    for (int j = 0; j < 4; ++j) {
        int i = base + t * 4 + j;
        if (i < n) s += cnt[i] + 1;  // +1 = self loop
    }
    for (int d = 1; d < 64; d <<= 1) s += __shfl_xor(s, d, 64);
    __shared__ int wsum[4];
    int lane = t & 63, wid = t >> 6;
    if (lane == 0) wsum[wid] = s;
    __syncthreads();
    if (t == 0) partials[b] = wsum[0] + wsum[1] + wsum[2] + wsum[3];
}

__global__ __launch_bounds__(256) void scan_p2(int* partials, int nb)
{
    __shared__ int buf[256];
    int t = threadIdx.x;
    int v = (t < nb) ? partials[t] : 0;
    buf[t] = v;
    __syncthreads();
    for (int d = 1; d < 256; d <<= 1) {
        int w = (t >= d) ? buf[t - d] : 0;
        __syncthreads();
        buf[t] += w;
        __syncthreads();
    }
    if (t < nb) partials[t] = buf[t] - v;  // exclusive
}

__global__ __launch_bounds__(256) void scan_p3(
    const int* __restrict__ cnt, const int* __restrict__ partials,
    int* __restrict__ offsets, int n)
{
    int b = blockIdx.x, t = threadIdx.x;
    int base = b * 1024;
    int v[4];
    int s = 0;
#pragma unroll
    for (int j = 0; j < 4; ++j) {
        int i = base + t * 4 + j;
        v[j] = (i < n) ? cnt[i] + 1 : 0;
        s += v[j];
    }
    int lane = t & 63, wid = t >> 6;
    int incl = s;
    for (int d = 1; d < 64; d <<= 1) {
        int w = __shfl_up(incl, d, 64);
        if (lane >= d) incl += w;
    }
    __shared__ int wsum[4];
    __shared__ int wbase[4];
    if (lane == 63) wsum[wid] = incl;
    __syncthreads();
    if (t == 0) {
        int r = 0;
        for (int i = 0; i < 4; ++i) { wbase[i] = r; r += wsum[i]; }
    }
    __syncthreads();
    int run = partials[b] + wbase[wid] + (incl - s);
#pragma unroll
    for (int j = 0; j < 4; ++j) {
        int i = base + t * 4 + j;
        if (i < n) {
            offsets[i] = run;
            run += v[j];
            if (i == n - 1) offsets[n] = run;
        }
    }
}

__global__ __launch_bounds__(256) void scatter_edges(
    const int* __restrict__ srcA, const int* __restrict__ dstA,
    const int* __restrict__ offsets, int* __restrict__ cursor,
    int* __restrict__ csr_src, int E, int N)
{
    int i = blockIdx.x * blockDim.x + threadIdx.x;
    if (i >= E + N) return;
    int s, d;
    if (i < E) { s = srcA[i]; d = dstA[i]; }
    else       { s = d = i - E; }
    int pos = offsets[d] + atomicAdd(&cursor[d], 1);
    csr_src[pos] = s;
}

// ---------------------------------------------------------------------------
// Kernel C: one wave (64 lanes) per destination node. Online softmax over
// in-edges; lane = output dim; h[src] gathered as coalesced 256B rows.
// Fused bias + row L2-normalize epilogue (wave shfl_xor reduction).
// ---------------------------------------------------------------------------
__global__ __launch_bounds__(256) void gat_pull(
    const int* __restrict__ offsets, const int* __restrict__ csr_src,
    const float* __restrict__ h, const float* __restrict__ a_src,
    const float* __restrict__ a_dst, const float* __restrict__ bias,
    float* __restrict__ out, int N)
{
    int wid = (blockIdx.x * blockDim.x + threadIdx.x) >> 6;  // node id
    int lane = threadIdx.x & 63;
    if (wid >= N) return;

    int beg = offsets[wid];
    int end = offsets[wid + 1];
    float ad = a_dst[wid];

    // software pipeline: fetch next src + score one edge ahead
    int src = csr_src[beg];
    float as = a_src[src];

    float m = -INFINITY, s = 0.f, acc = 0.f;
    for (int p = beg; p < end; ++p) {
        float hv = h[(size_t)src * C_OUT + lane];  // coalesced 256B gather
        int np = (p + 1 < end) ? p + 1 : beg;
        int nsrc = csr_src[np];
        float nas = a_src[nsrc];

        float e = as + ad;
        e = (e > 0.f) ? e : NEG_SLOPE * e;
        float m2 = fmaxf(m, e);
        float sc = __expf(m - m2);   // first iter: exp(-inf) = 0
        float pe = __expf(e - m2);
        s = s * sc + pe;
        acc = acc * sc + pe * hv;
        m = m2;

        src = nsrc;
        as = nas;
    }

    float o = acc / s + bias[lane];

    // row L2 norm across the 64 lanes
    float sq = o * o;
#pragma unroll
    for (int d = 1; d < 64; d <<= 1) sq += __shfl_xor(sq, d, 64);
    float nrm = fmaxf(sqrtf(sq), EPS_NRM);

    out[(size_t)wid * C_OUT + lane] = o / nrm;
}

// ---------------------------------------------------------------------------
extern "C" void kernel_launch(void* const* d_in, const int* in_sizes, int n_in,
                              void* d_out, int out_size, void* d_ws, size_t ws_size,
                              hipStream_t stream)
{
    const float* x     = (const float*)d_in[0];
    const int*   ei    = (const int*)d_in[1];   // [2][E], row0=src, row1=dst
    const float* W     = (const float*)d_in[2];
    const float* att_s = (const float*)d_in[3];
    const float* att_d = (const float*)d_in[4];
    const float* bias  = (const float*)d_in[5];
    float*       out   = (float*)d_out;

    const int OUT = in_sizes[3];          // 64
    const int IN  = in_sizes[2] / OUT;    // 256
    const int N   = in_sizes[0] / IN;     // 100000
    const int E   = in_sizes[1] / 2;      // 1600000

    // workspace carve-out (256B aligned)
    char* w = (char*)d_ws;
    auto alloc = [&](size_t bytes) -> void* {
        void* p = (void*)w;
        w += (bytes + 255) & ~(size_t)255;
        return p;
    };
    float* h      = (float*)alloc((size_t)N * C_OUT * 4);
    float* a_src  = (float*)alloc((size_t)N * 4);
    float* a_dst  = (float*)alloc((size_t)N * 4);
    int*   cnt    = (int*)alloc((size_t)N * 4);
    int*   cursor = (int*)alloc((size_t)N * 4);
    int*   offs   = (int*)alloc((size_t)(N + 1) * 4);
    int*   parts  = (int*)alloc(1024 * 4);
    int*   csr    = (int*)alloc((size_t)(E + N) * 4);

    hipMemsetAsync(cnt, 0, (size_t)N * 4, stream);
    hipMemsetAsync(cursor, 0, (size_t)N * 4, stream);

    gemm_att<<<(N + 255) / 256, 256, 0, stream>>>(x, W, att_s, att_d,
                                                  h, a_src, a_dst, N);

    count_dst<<<(E + 255) / 256, 256, 0, stream>>>(ei + E, cnt, E);

    int NB = (N + 1023) / 1024;
    scan_p1<<<NB, 256, 0, stream>>>(cnt, parts, N);
    scan_p2<<<1, 256, 0, stream>>>(parts, NB);
    scan_p3<<<NB, 256, 0, stream>>>(cnt, parts, offs, N);

    scatter_edges<<<(E + N + 255) / 256, 256, 0, stream>>>(ei, ei + E, offs,
                                                           cursor, csr, E, N);

    gat_pull<<<(N + 3) / 4, 256, 0, stream>>>(offs, csr, h, a_src, a_dst,
                                              bias, out, N);
}